// Round 8
// baseline (291.614 us; speedup 1.0000x reference)
//
#include <hip/hip_runtime.h>
#include <math.h>

#define BATCH 2
#define NCH 21
#define CPAD 24            // channels padded to 24 (48 B fp16 per pixel)
#define WUPAD 48           // packed per-pixel w(24) + u(21) + w24 + pad = 48 halfs (96 B)
#define HH 512
#define WW 512
#define KS 5
#define RAD 2
#define NTAPS 25
#define NUM_ITERS 10

// setup-kernel tile geometry (weights part): 32x16, 512 threads
#define TXW 32
#define TYW 16
#define HXW (TXW + 2*RAD)   // 36
#define HYW (TYW + 2*RAD)   // 20
#define HPXW (HXW * HYW)    // 720

// fused-pair kernel geometry: 32x16 inner tile, 512 threads (PROVEN 287-us baseline)
#define TW 32
#define TH 16
#define NTHR 512
#define SX 40               // staged tile (4-px halo for 2 iters)
#define SY 24
#define SPX (SX * SY)       // 960
#define SCHUNK (SPX * 3)    // 2880 16-byte DMA chunks
#define EX 36               // extended (iter-1 output) region
#define EY 20
#define EPX (EX * EY)       // 720
#define RING (EPX - TW*TH)  // 208 ring pixels

typedef _Float16 f16;
typedef _Float16 half8 __attribute__((ext_vector_type(8)));
typedef _Float16 half2v __attribute__((ext_vector_type(2)));

__device__ __forceinline__ int refl(int i, int n) {
    if (i < 0) i = -i;
    if (i >= n) i = 2*n - 2 - i;
    return i;
}

// weight-element selector (t is a compile-time constant after unrolling)
#define WSEL(h0, h1, h2, hl, t) \
    ((t) < 8 ? (h0)[(t)] : (t) < 16 ? (h1)[(t) - 8] : (t) < 24 ? (h2)[(t) - 16] : (hl))

// ---------------- Kernel A: fused weights + init (one thread per pixel) ----------------
// Writes the packed per-pixel record wu[px][48]: [0:24)=w0..w23, [24:45)=u0..u20,
// [45]=w24, [46:48)=pad. __launch_bounds__(512,4): VGPR cap 64 (CUDA-style min-blocks,
// R2/R3 A/B) -> 4 blocks/CU resident = 32 waves/CU, no trailing generation. Natural
// allocation was 68 (3 resident + tail); 4-reg shave is rematerialization range.
__global__ __launch_bounds__(512, 4) void setup_kernel(const float* __restrict__ image,
                                                       const float* __restrict__ edges,
                                                       const float* __restrict__ unary,
                                                       f16* __restrict__ wu,
                                                       f16* __restrict__ q) {
    __shared__ float sr_[HYW][HXW];
    __shared__ float sg_[HYW][HXW];
    __shared__ float sb_[HYW][HXW];
    __shared__ float se_[HYW][HXW];

    const int tx = threadIdx.x;
    const int ty = threadIdx.y;
    const int tid = ty * TXW + tx;
    const int x0 = blockIdx.x * TXW;
    const int y0 = blockIdx.y * TYW;
    const int b = blockIdx.z;
    const int x = x0 + tx;
    const int y = y0 + ty;
    const size_t plane = (size_t)HH * WW;
    const float* img = image + (size_t)b * 3 * plane;
    const float* edg = edges + (size_t)b * plane;

    for (int i = tid; i < HPXW; i += TXW * TYW) {
        int ly = i / HXW, lx = i - ly * HXW;
        int gy = refl(y0 + ly - RAD, HH);
        int gx = refl(x0 + lx - RAD, WW);
        int g = gy * WW + gx;
        sr_[ly][lx] = img[g];
        sg_[ly][lx] = img[plane + g];
        sb_[ly][lx] = img[2 * plane + g];
        se_[ly][lx] = edg[g];
    }

    // ---- issue init's unary loads BEFORE the barrier: latency hides under staging ----
    float l[NCH];
    {
        const float* u = unary + (size_t)b * NCH * plane + (size_t)y * WW + x;
#pragma unroll
        for (int c = 0; c < NCH; c++) l[c] = u[c * plane];
    }

    __syncthreads();

    float gs[3];
    gs[0] = 1.0f; gs[1] = __expf(-1.0f / 50.0f); gs[2] = __expf(-4.0f / 50.0f);
    float gb[3];
    gb[0] = 1.0f; gb[1] = __expf(-2.0f); gb[2] = __expf(-8.0f);
    float gbs = gb[0] + 2.0f * (gb[1] + gb[2]);
    gb[0] /= gbs; gb[1] /= gbs; gb[2] /= gbs;

    const float r0 = sr_[ty + RAD][tx + RAD];
    const float g0 = sg_[ty + RAD][tx + RAD];
    const float b0 = sb_[ty + RAD][tx + RAD];
    const float e0 = se_[ty + RAD][tx + RAD];

    float wr[NTAPS], we[NTAPS];
    float sr = 0.f, se = 0.f;
#pragma unroll
    for (int dy = 0; dy < KS; dy++) {
#pragma unroll
        for (int dx = 0; dx < KS; dx++) {
            float sp = gs[abs(dy - RAD)] * gs[abs(dx - RAD)];
            float d = fabsf(sr_[ty + dy][tx + dx] - r0)
                    + fabsf(sg_[ty + dy][tx + dx] - g0)
                    + fabsf(sb_[ty + dy][tx + dx] - b0);
            float w1 = sp * __expf(-2.0f * d * d);
            float de = fabsf(se_[ty + dy][tx + dx] - e0);
            float w2 = sp * __expf(-2.0f * de * de);
            wr[dy * KS + dx] = w1;
            we[dy * KS + dx] = w2;
            sr += w1;
            se += w2;
        }
    }
    float isr = 1.0f / sr, ise = 1.0f / se;
    float wt[NTAPS];
#pragma unroll
    for (int t = 0; t < NTAPS; t++) {
        int dy = t / KS, dx = t % KS;
        float g2 = gb[abs(dy - RAD)] * gb[abs(dx - RAD)];
        wt[t] = g2 + wr[t] * isr + we[t] * ise;
    }
    const size_t pixoff = (size_t)b * plane + (size_t)y * WW + x;

    // ---- packed wu record: 6 contiguous half8 stores ----
    {
        half8* wo = (half8*)(wu + pixoff * WUPAD);
        half8 v;
#pragma unroll
        for (int k = 0; k < 8; k++) v[k] = (f16)wt[k];
        wo[0] = v;
#pragma unroll
        for (int k = 0; k < 8; k++) v[k] = (f16)wt[8 + k];
        wo[1] = v;
#pragma unroll
        for (int k = 0; k < 8; k++) v[k] = (f16)wt[16 + k];
        wo[2] = v;
#pragma unroll
        for (int k = 0; k < 8; k++) v[k] = (f16)l[k];
        wo[3] = v;
#pragma unroll
        for (int k = 0; k < 8; k++) v[k] = (f16)l[8 + k];
        wo[4] = v;
#pragma unroll
        for (int k = 0; k < 5; k++) v[k] = (f16)l[16 + k];
        v[5] = (f16)wt[24];
        v[6] = (f16)0.f; v[7] = (f16)0.f;
        wo[5] = v;
    }

    // ---- init softmax -> q ----
    {
        float m = l[0];
#pragma unroll
        for (int c = 1; c < NCH; c++) m = fmaxf(m, l[c]);
        float e[NCH];
        float s = 0.f;
#pragma unroll
        for (int c = 0; c < NCH; c++) { e[c] = __expf(l[c] - m); s += e[c]; }
        float is = 1.0f / s;
        half8* qo = (half8*)(q + pixoff * CPAD);
        half8 v;
#pragma unroll
        for (int k = 0; k < 8; k++) v[k] = (f16)(e[k] * is);
        qo[0] = v;
#pragma unroll
        for (int k = 0; k < 8; k++) v[k] = (f16)(e[8 + k] * is);
        qo[1] = v;
#pragma unroll
        for (int k = 0; k < 5; k++) v[k] = (f16)(e[16 + k] * is);
        v[5] = (f16)0.f; v[6] = (f16)0.f; v[7] = (f16)0.f;
        qo[2] = v;
    }
}

// packed-f16 conv helper: 25-tap gather, v_pk_fma_f16 (11 packed MACs per tap)
#define CONV_ACC_PK(acc2, lds, row0, col0, stride, W0, W1, W2, WL)                     \
    {                                                                                  \
        _Pragma("unroll")                                                              \
        for (int dy = 0; dy < KS; dy++) {                                              \
            _Pragma("unroll")                                                          \
            for (int dx = 0; dx < KS; dx++) {                                          \
                const f16 wt_ = WSEL(W0, W1, W2, WL, dy * KS + dx);                    \
                const half2v wv_ = {wt_, wt_};                                         \
                const f16* tp = (lds) + ((size_t)((row0) + dy) * (stride) + (col0) + dx) * CPAD; \
                half8 v0 = *(const half8*)(tp);                                        \
                half8 v1 = *(const half8*)(tp + 8);                                    \
                half8 v2 = *(const half8*)(tp + 16);                                   \
                acc2[0]  = __builtin_elementwise_fma(wv_, __builtin_shufflevector(v0, v0, 0, 1), acc2[0]);  \
                acc2[1]  = __builtin_elementwise_fma(wv_, __builtin_shufflevector(v0, v0, 2, 3), acc2[1]);  \
                acc2[2]  = __builtin_elementwise_fma(wv_, __builtin_shufflevector(v0, v0, 4, 5), acc2[2]);  \
                acc2[3]  = __builtin_elementwise_fma(wv_, __builtin_shufflevector(v0, v0, 6, 7), acc2[3]);  \
                acc2[4]  = __builtin_elementwise_fma(wv_, __builtin_shufflevector(v1, v1, 0, 1), acc2[4]);  \
                acc2[5]  = __builtin_elementwise_fma(wv_, __builtin_shufflevector(v1, v1, 2, 3), acc2[5]);  \
                acc2[6]  = __builtin_elementwise_fma(wv_, __builtin_shufflevector(v1, v1, 4, 5), acc2[6]);  \
                acc2[7]  = __builtin_elementwise_fma(wv_, __builtin_shufflevector(v1, v1, 6, 7), acc2[7]);  \
                acc2[8]  = __builtin_elementwise_fma(wv_, __builtin_shufflevector(v2, v2, 0, 1), acc2[8]);  \
                acc2[9]  = __builtin_elementwise_fma(wv_, __builtin_shufflevector(v2, v2, 2, 3), acc2[9]);  \
                acc2[10] = __builtin_elementwise_fma(wv_, __builtin_shufflevector(v2, v2, 4, 5), acc2[10]); \
            }                                                                          \
        }                                                                              \
    }

// logits: l[c] = u[c] - acc2 (promote f16 acc to f32 here)
#define LOGITS_FROM_PK(l, acc2, U0, U1, U2)                                            \
    {                                                                                  \
        _Pragma("unroll")                                                              \
        for (int j = 0; j < 10; j++) {                                                 \
            l[2 * j]     = -(float)acc2[j][0];                                         \
            l[2 * j + 1] = -(float)acc2[j][1];                                         \
        }                                                                              \
        l[20] = -(float)acc2[10][0];                                                   \
        _Pragma("unroll")                                                              \
        for (int k = 0; k < 8; k++) l[k] += (float)U0[k];                              \
        _Pragma("unroll")                                                              \
        for (int k = 0; k < 8; k++) l[8 + k] += (float)U1[k];                          \
        _Pragma("unroll")                                                              \
        for (int k = 0; k < 5; k++) l[16 + k] += (float)U2[k];                         \
    }

// ---------------- Kernel C: TWO fused CRF iterations per launch (PROVEN 287-us body) ----
template <bool FINAL>
__global__ __launch_bounds__(NTHR, 4) void crf_pair_kernel(const f16* __restrict__ qin,
                                                           const f16* __restrict__ wu,
                                                           void* __restrict__ qout) {
    __shared__ __align__(16) f16 buf[SPX][CPAD];   // 46080 B; staged q, then reused for q'

    const int tid = threadIdx.x;          // 0..511
    const int ix = tid & (TW - 1);        // 0..31
    const int iy = tid >> 5;              // 0..15

    // XCD band swizzle: 1024 blocks; XCD (flat%8) owns 4 tile-rows per batch
    const int flat = blockIdx.x;
    const int band = flat & 7;
    const int within = flat >> 3;         // 0..127
    const int b = within >> 6;
    const int r = within & 63;
    const int x0 = (r & 15) * TW;
    const int y0 = (band * 4 + (r >> 4)) * TH;
    const int gx = x0 + ix;
    const int gy = y0 + iy;
    const size_t plane = (size_t)HH * WW;

    // ---- phase 1: async stage 24x40 q halo (4-px, for 2 iterations) ----
    const f16* qbase = qin + (size_t)b * plane * CPAD;
    f16* lbase = &buf[0][0];
    for (int idx = tid; idx < SCHUNK; idx += NTHR) {
        int px = idx / 3, h4 = idx - px * 3;
        int sly = px / SX, slx = px - sly * SX;
        int qy = refl(y0 - 4 + sly, HH);
        int qx = refl(x0 - 4 + slx, WW);
        const f16* g = qbase + ((size_t)(qy * WW + qx)) * CPAD + h4 * 8;
        __builtin_amdgcn_global_load_lds(
            (const __attribute__((address_space(1))) void*)g,
            (__attribute__((address_space(3))) void*)(lbase + (size_t)idx * 8),
            16, 0, 0);
    }

    // ---- fetch inner-pixel packed w+u (registers, used by BOTH iterations) ----
    const size_t pixoff = (size_t)b * plane + (size_t)gy * WW + gx;
    const half8* wp = (const half8*)(wu + pixoff * WUPAD);
    half8 wa0 = wp[0], wa1 = wp[1], wa2 = wp[2];
    half8 ui0 = wp[3], ui1 = wp[4], ui2 = wp[5];
    f16 wl = ui2[5];

    // ---- ring pixel (threads 0..207): coords + packed w+u ----
    const bool has_ring = tid < RING;
    int rly = 0, rlx = 0;
    half8 wr0 = {}, wr1 = {}, wr2 = {}, ur0 = {}, ur1 = {}, ur2 = {};
    f16 wrl = (f16)0.f;
    if (has_ring) {
        int t = tid;
        if (t < 72)       { rly = t / 36;       rlx = t % 36; }
        else if (t < 144) { t -= 72;  rly = 18 + t / 36; rlx = t % 36; }
        else              { t -= 144; rly = 2 + (t >> 2); int c = t & 3; rlx = (c < 2) ? c : (c + 32); }
        int rgy = y0 + rly - 2, rgx = x0 + rlx - 2;
        int cy = min(max(rgy, 0), HH - 1);
        int cx = min(max(rgx, 0), WW - 1);
        size_t rpo = (size_t)b * plane + (size_t)cy * WW + cx;
        const half8* wpr = (const half8*)(wu + rpo * WUPAD);
        wr0 = wpr[0]; wr1 = wpr[1]; wr2 = wpr[2];
        ur0 = wpr[3]; ur1 = wpr[4]; ur2 = wpr[5];
        wrl = ur2[5];
    }

    __syncthreads();   // staged q + register loads resident

    // ---- phase 2: iteration k over the extended 36x20 region (packed f16 MACs) ----
    half8 qr0, qr1, qr2;   // ring q' (packed f16)
    if (has_ring) {
        half2v acc2[11];
#pragma unroll
        for (int j = 0; j < 11; j++) acc2[j] = (half2v){(f16)0.f, (f16)0.f};
        CONV_ACC_PK(acc2, lbase, rly, rlx, SX, wr0, wr1, wr2, wrl);
        float l[NCH];
        LOGITS_FROM_PK(l, acc2, ur0, ur1, ur2);
        float m = l[0];
#pragma unroll
        for (int c = 1; c < NCH; c++) m = fmaxf(m, l[c]);
        float s = 0.f;
#pragma unroll
        for (int c = 0; c < NCH; c++) { l[c] = __expf(l[c] - m); s += l[c]; }
        float is = 1.0f / s;
#pragma unroll
        for (int k = 0; k < 8; k++) qr0[k] = (f16)(l[k] * is);
#pragma unroll
        for (int k = 0; k < 8; k++) qr1[k] = (f16)(l[8 + k] * is);
#pragma unroll
        for (int k = 0; k < 5; k++) qr2[k] = (f16)(l[16 + k] * is);
        qr2[5] = (f16)0.f; qr2[6] = (f16)0.f; qr2[7] = (f16)0.f;
    }

    half8 qi0, qi1, qi2;   // inner q' (packed f16)
    {
        half2v acc2[11];
#pragma unroll
        for (int j = 0; j < 11; j++) acc2[j] = (half2v){(f16)0.f, (f16)0.f};
        CONV_ACC_PK(acc2, lbase, iy + 2, ix + 2, SX, wa0, wa1, wa2, wl);
        float l[NCH];
        LOGITS_FROM_PK(l, acc2, ui0, ui1, ui2);
        float m = l[0];
#pragma unroll
        for (int c = 1; c < NCH; c++) m = fmaxf(m, l[c]);
        float s = 0.f;
#pragma unroll
        for (int c = 0; c < NCH; c++) { l[c] = __expf(l[c] - m); s += l[c]; }
        float is = 1.0f / s;
#pragma unroll
        for (int k = 0; k < 8; k++) qi0[k] = (f16)(l[k] * is);
#pragma unroll
        for (int k = 0; k < 8; k++) qi1[k] = (f16)(l[8 + k] * is);
#pragma unroll
        for (int k = 0; k < 5; k++) qi2[k] = (f16)(l[16 + k] * is);
        qi2[5] = (f16)0.f; qi2[6] = (f16)0.f; qi2[7] = (f16)0.f;
    }

    __syncthreads();   // all reads of staged q complete

    // ---- phase 3: park q' in LDS (reuse buf; layout [EPX][24], stride EX) ----
    {
        half8* d = (half8*)(lbase + ((size_t)(iy + 2) * EX + (ix + 2)) * CPAD);
        d[0] = qi0; d[1] = qi1; d[2] = qi2;
        if (has_ring) {
            half8* dr = (half8*)(lbase + ((size_t)rly * EX + rlx) * CPAD);
            dr[0] = qr0; dr[1] = qr1; dr[2] = qr2;
        }
    }

    __syncthreads();

    // ---- phase 4: iteration k+1 at inner pixels (w,u from registers) ----
    {
        int ry[KS], rx[KS];
#pragma unroll
        for (int d = 0; d < KS; d++) {
            ry[d] = refl(gy + d - 2, HH) - (y0 - 2);
            rx[d] = refl(gx + d - 2, WW) - (x0 - 2);
        }
        half2v acc2[11];
#pragma unroll
        for (int j = 0; j < 11; j++) acc2[j] = (half2v){(f16)0.f, (f16)0.f};
#pragma unroll
        for (int dy = 0; dy < KS; dy++) {
#pragma unroll
            for (int dx = 0; dx < KS; dx++) {
                const f16 wt_ = WSEL(wa0, wa1, wa2, wl, dy * KS + dx);
                const half2v wv_ = {wt_, wt_};
                const f16* tp = lbase + ((size_t)ry[dy] * EX + rx[dx]) * CPAD;
                half8 v0 = *(const half8*)(tp);
                half8 v1 = *(const half8*)(tp + 8);
                half8 v2 = *(const half8*)(tp + 16);
                acc2[0]  = __builtin_elementwise_fma(wv_, __builtin_shufflevector(v0, v0, 0, 1), acc2[0]);
                acc2[1]  = __builtin_elementwise_fma(wv_, __builtin_shufflevector(v0, v0, 2, 3), acc2[1]);
                acc2[2]  = __builtin_elementwise_fma(wv_, __builtin_shufflevector(v0, v0, 4, 5), acc2[2]);
                acc2[3]  = __builtin_elementwise_fma(wv_, __builtin_shufflevector(v0, v0, 6, 7), acc2[3]);
                acc2[4]  = __builtin_elementwise_fma(wv_, __builtin_shufflevector(v1, v1, 0, 1), acc2[4]);
                acc2[5]  = __builtin_elementwise_fma(wv_, __builtin_shufflevector(v1, v1, 2, 3), acc2[5]);
                acc2[6]  = __builtin_elementwise_fma(wv_, __builtin_shufflevector(v1, v1, 4, 5), acc2[6]);
                acc2[7]  = __builtin_elementwise_fma(wv_, __builtin_shufflevector(v1, v1, 6, 7), acc2[7]);
                acc2[8]  = __builtin_elementwise_fma(wv_, __builtin_shufflevector(v2, v2, 0, 1), acc2[8]);
                acc2[9]  = __builtin_elementwise_fma(wv_, __builtin_shufflevector(v2, v2, 2, 3), acc2[9]);
                acc2[10] = __builtin_elementwise_fma(wv_, __builtin_shufflevector(v2, v2, 4, 5), acc2[10]);
            }
        }
        float l[NCH];
        LOGITS_FROM_PK(l, acc2, ui0, ui1, ui2);
        float m = l[0];
#pragma unroll
        for (int c = 1; c < NCH; c++) m = fmaxf(m, l[c]);
        float s = 0.f;
#pragma unroll
        for (int c = 0; c < NCH; c++) { l[c] = __expf(l[c] - m); s += l[c]; }
        float is = 1.0f / s;

        if (FINAL) {
            float* qo = (float*)qout + (size_t)b * NCH * plane + (size_t)gy * WW + gx;
#pragma unroll
            for (int c = 0; c < NCH; c++) qo[c * plane] = l[c] * is;
        } else {
            half8* qo = (half8*)((f16*)qout + pixoff * CPAD);
            half8 o0, o1, o2;
#pragma unroll
            for (int k = 0; k < 8; k++) o0[k] = (f16)(l[k] * is);
#pragma unroll
            for (int k = 0; k < 8; k++) o1[k] = (f16)(l[8 + k] * is);
#pragma unroll
            for (int k = 0; k < 5; k++) o2[k] = (f16)(l[16 + k] * is);
            o2[5] = (f16)0.f; o2[6] = (f16)0.f; o2[7] = (f16)0.f;
            qo[0] = o0; qo[1] = o1; qo[2] = o2;
        }
    }
}

extern "C" void kernel_launch(void* const* d_in, const int* in_sizes, int n_in,
                              void* d_out, int out_size, void* d_ws, size_t ws_size,
                              hipStream_t stream) {
    const float* unary = (const float*)d_in[0];   // B,21,512,512
    const float* image = (const float*)d_in[1];   // B,3,512,512
    const float* edges = (const float*)d_in[2];   // B,512,512
    float* out = (float*)d_out;                   // B,21,512,512 fp32

    const size_t plane = (size_t)HH * WW;
    char* ws = (char*)d_ws;
    f16* wu = (f16*)ws;                                          // B*plane*48 f16 = 50.3 MB
    char* p1 = ws + sizeof(f16) * BATCH * plane * WUPAD;
    f16* qA = (f16*)p1;                                          // 25.2 MB
    f16* qB = qA + (size_t)BATCH * plane * CPAD;                 // 25.2 MB (total ~101 MB)

    dim3 gridW(WW / TXW, HH / TYW, BATCH);
    dim3 blockW(TXW, TYW, 1);
    setup_kernel<<<gridW, blockW, 0, stream>>>(image, edges, unary, wu, qA);

    const int nblk = (WW / TW) * (HH / TH) * BATCH;   // 1024
    f16* qa = qA;
    f16* qb = qB;
    const int npairs = NUM_ITERS / 2;                 // 5
    for (int it = 0; it < npairs - 1; it++) {
        crf_pair_kernel<false><<<nblk, NTHR, 0, stream>>>(qa, wu, (void*)qb);
        f16* t = qa; qa = qb; qb = t;
    }
    crf_pair_kernel<true><<<nblk, NTHR, 0, stream>>>(qa, wu, (void*)out);
}

// Round 9
// 283.014 us; speedup vs baseline: 1.0304x; 1.0304x over previous
//
#include <hip/hip_runtime.h>
#include <math.h>

#define BATCH 2
#define NCH 21
#define CPAD 24            // channels padded to 24 (48 B fp16 per pixel)
#define WUPAD 48           // packed per-pixel w(24) + u(21) + w24 + pad = 48 halfs (96 B)
#define HH 512
#define WW 512
#define KS 5
#define RAD 2
#define NTAPS 25
#define NUM_ITERS 10

// setup-kernel tile geometry (weights part): 32x16, 512 threads
#define TXW 32
#define TYW 16
#define HXW (TXW + 2*RAD)   // 36
#define HYW (TYW + 2*RAD)   // 20
#define HPXW (HXW * HYW)    // 720

// fused-pair kernel geometry: 32x16 inner tile, 512 threads (PROVEN 287-us baseline)
#define TW 32
#define TH 16
#define NTHR 512
#define SX 40               // staged tile (4-px halo for 2 iters)
#define SY 24
#define SPX (SX * SY)       // 960
#define SCHUNK (SPX * 3)    // 2880 16-byte DMA chunks
#define EX 36               // extended (iter-1 output) region
#define EY 20
#define EPX (EX * EY)       // 720
#define RING (EPX - TW*TH)  // 208 ring pixels

typedef _Float16 f16;
typedef _Float16 half8 __attribute__((ext_vector_type(8)));
typedef _Float16 half2v __attribute__((ext_vector_type(2)));

__device__ __forceinline__ int refl(int i, int n) {
    if (i < 0) i = -i;
    if (i >= n) i = 2*n - 2 - i;
    return i;
}

// weight-element selector (t is a compile-time constant after unrolling)
#define WSEL(h0, h1, h2, hl, t) \
    ((t) < 8 ? (h0)[(t)] : (t) < 16 ? (h1)[(t) - 8] : (t) < 24 ? (h2)[(t) - 16] : (hl))

// ---------------- Kernel A: fused weights + init (one thread per pixel) ----------------
// Packed-LDS variant: {r,g,b,e} in one float4 array -> the 25-tap loop issues 25
// ds_read_b128 instead of 100 ds_read_b32. Arithmetic identical (same add order).
// NO min-blocks bound: R7 proved capping below the natural 68 VGPR converts registers
// to ~24 MB of scratch traffic (WRITE 74->97 MB, dur 42->48 us).
__global__ __launch_bounds__(512) void setup_kernel(const float* __restrict__ image,
                                                    const float* __restrict__ edges,
                                                    const float* __restrict__ unary,
                                                    f16* __restrict__ wu,
                                                    f16* __restrict__ q) {
    __shared__ __align__(16) float4 spx[HYW][HXW];   // {r,g,b,e}, 11520 B

    const int tx = threadIdx.x;
    const int ty = threadIdx.y;
    const int tid = ty * TXW + tx;
    const int x0 = blockIdx.x * TXW;
    const int y0 = blockIdx.y * TYW;
    const int b = blockIdx.z;
    const int x = x0 + tx;
    const int y = y0 + ty;
    const size_t plane = (size_t)HH * WW;
    const float* img = image + (size_t)b * 3 * plane;
    const float* edg = edges + (size_t)b * plane;

    for (int i = tid; i < HPXW; i += TXW * TYW) {
        int ly = i / HXW, lx = i - ly * HXW;
        int gy = refl(y0 + ly - RAD, HH);
        int gx = refl(x0 + lx - RAD, WW);
        int g = gy * WW + gx;
        float4 v;
        v.x = img[g];
        v.y = img[plane + g];
        v.z = img[2 * plane + g];
        v.w = edg[g];
        spx[ly][lx] = v;
    }

    // ---- issue init's unary loads BEFORE the barrier: latency hides under staging ----
    float l[NCH];
    {
        const float* u = unary + (size_t)b * NCH * plane + (size_t)y * WW + x;
#pragma unroll
        for (int c = 0; c < NCH; c++) l[c] = u[c * plane];
    }

    __syncthreads();

    float gs[3];
    gs[0] = 1.0f; gs[1] = __expf(-1.0f / 50.0f); gs[2] = __expf(-4.0f / 50.0f);
    float gb[3];
    gb[0] = 1.0f; gb[1] = __expf(-2.0f); gb[2] = __expf(-8.0f);
    float gbs = gb[0] + 2.0f * (gb[1] + gb[2]);
    gb[0] /= gbs; gb[1] /= gbs; gb[2] /= gbs;

    const float4 c0 = spx[ty + RAD][tx + RAD];
    const float r0 = c0.x, g0 = c0.y, b0 = c0.z, e0 = c0.w;

    float wr[NTAPS], we[NTAPS];
    float sr = 0.f, se = 0.f;
#pragma unroll
    for (int dy = 0; dy < KS; dy++) {
#pragma unroll
        for (int dx = 0; dx < KS; dx++) {
            float sp = gs[abs(dy - RAD)] * gs[abs(dx - RAD)];
            float4 v = spx[ty + dy][tx + dx];
            float d = fabsf(v.x - r0)
                    + fabsf(v.y - g0)
                    + fabsf(v.z - b0);
            float w1 = sp * __expf(-2.0f * d * d);
            float de = fabsf(v.w - e0);
            float w2 = sp * __expf(-2.0f * de * de);
            wr[dy * KS + dx] = w1;
            we[dy * KS + dx] = w2;
            sr += w1;
            se += w2;
        }
    }
    float isr = 1.0f / sr, ise = 1.0f / se;
    float wt[NTAPS];
#pragma unroll
    for (int t = 0; t < NTAPS; t++) {
        int dy = t / KS, dx = t % KS;
        float g2 = gb[abs(dy - RAD)] * gb[abs(dx - RAD)];
        wt[t] = g2 + wr[t] * isr + we[t] * ise;
    }
    const size_t pixoff = (size_t)b * plane + (size_t)y * WW + x;

    // ---- packed wu record: 6 contiguous half8 stores ----
    {
        half8* wo = (half8*)(wu + pixoff * WUPAD);
        half8 v;
#pragma unroll
        for (int k = 0; k < 8; k++) v[k] = (f16)wt[k];
        wo[0] = v;
#pragma unroll
        for (int k = 0; k < 8; k++) v[k] = (f16)wt[8 + k];
        wo[1] = v;
#pragma unroll
        for (int k = 0; k < 8; k++) v[k] = (f16)wt[16 + k];
        wo[2] = v;
#pragma unroll
        for (int k = 0; k < 8; k++) v[k] = (f16)l[k];
        wo[3] = v;
#pragma unroll
        for (int k = 0; k < 8; k++) v[k] = (f16)l[8 + k];
        wo[4] = v;
#pragma unroll
        for (int k = 0; k < 5; k++) v[k] = (f16)l[16 + k];
        v[5] = (f16)wt[24];
        v[6] = (f16)0.f; v[7] = (f16)0.f;
        wo[5] = v;
    }

    // ---- init softmax -> q ----
    {
        float m = l[0];
#pragma unroll
        for (int c = 1; c < NCH; c++) m = fmaxf(m, l[c]);
        float e[NCH];
        float s = 0.f;
#pragma unroll
        for (int c = 0; c < NCH; c++) { e[c] = __expf(l[c] - m); s += e[c]; }
        float is = 1.0f / s;
        half8* qo = (half8*)(q + pixoff * CPAD);
        half8 v;
#pragma unroll
        for (int k = 0; k < 8; k++) v[k] = (f16)(e[k] * is);
        qo[0] = v;
#pragma unroll
        for (int k = 0; k < 8; k++) v[k] = (f16)(e[8 + k] * is);
        qo[1] = v;
#pragma unroll
        for (int k = 0; k < 5; k++) v[k] = (f16)(e[16 + k] * is);
        v[5] = (f16)0.f; v[6] = (f16)0.f; v[7] = (f16)0.f;
        qo[2] = v;
    }
}

// packed-f16 conv helper: 25-tap gather, v_pk_fma_f16 (11 packed MACs per tap)
#define CONV_ACC_PK(acc2, lds, row0, col0, stride, W0, W1, W2, WL)                     \
    {                                                                                  \
        _Pragma("unroll")                                                              \
        for (int dy = 0; dy < KS; dy++) {                                              \
            _Pragma("unroll")                                                          \
            for (int dx = 0; dx < KS; dx++) {                                          \
                const f16 wt_ = WSEL(W0, W1, W2, WL, dy * KS + dx);                    \
                const half2v wv_ = {wt_, wt_};                                         \
                const f16* tp = (lds) + ((size_t)((row0) + dy) * (stride) + (col0) + dx) * CPAD; \
                half8 v0 = *(const half8*)(tp);                                        \
                half8 v1 = *(const half8*)(tp + 8);                                    \
                half8 v2 = *(const half8*)(tp + 16);                                   \
                acc2[0]  = __builtin_elementwise_fma(wv_, __builtin_shufflevector(v0, v0, 0, 1), acc2[0]);  \
                acc2[1]  = __builtin_elementwise_fma(wv_, __builtin_shufflevector(v0, v0, 2, 3), acc2[1]);  \
                acc2[2]  = __builtin_elementwise_fma(wv_, __builtin_shufflevector(v0, v0, 4, 5), acc2[2]);  \
                acc2[3]  = __builtin_elementwise_fma(wv_, __builtin_shufflevector(v0, v0, 6, 7), acc2[3]);  \
                acc2[4]  = __builtin_elementwise_fma(wv_, __builtin_shufflevector(v1, v1, 0, 1), acc2[4]);  \
                acc2[5]  = __builtin_elementwise_fma(wv_, __builtin_shufflevector(v1, v1, 2, 3), acc2[5]);  \
                acc2[6]  = __builtin_elementwise_fma(wv_, __builtin_shufflevector(v1, v1, 4, 5), acc2[6]);  \
                acc2[7]  = __builtin_elementwise_fma(wv_, __builtin_shufflevector(v1, v1, 6, 7), acc2[7]);  \
                acc2[8]  = __builtin_elementwise_fma(wv_, __builtin_shufflevector(v2, v2, 0, 1), acc2[8]);  \
                acc2[9]  = __builtin_elementwise_fma(wv_, __builtin_shufflevector(v2, v2, 2, 3), acc2[9]);  \
                acc2[10] = __builtin_elementwise_fma(wv_, __builtin_shufflevector(v2, v2, 4, 5), acc2[10]); \
            }                                                                          \
        }                                                                              \
    }

// logits: l[c] = u[c] - acc2 (promote f16 acc to f32 here)
#define LOGITS_FROM_PK(l, acc2, U0, U1, U2)                                            \
    {                                                                                  \
        _Pragma("unroll")                                                              \
        for (int j = 0; j < 10; j++) {                                                 \
            l[2 * j]     = -(float)acc2[j][0];                                         \
            l[2 * j + 1] = -(float)acc2[j][1];                                         \
        }                                                                              \
        l[20] = -(float)acc2[10][0];                                                   \
        _Pragma("unroll")                                                              \
        for (int k = 0; k < 8; k++) l[k] += (float)U0[k];                              \
        _Pragma("unroll")                                                              \
        for (int k = 0; k < 8; k++) l[8 + k] += (float)U1[k];                          \
        _Pragma("unroll")                                                              \
        for (int k = 0; k < 5; k++) l[16 + k] += (float)U2[k];                         \
    }

// ---------------- Kernel C: TWO fused CRF iterations per launch (PROVEN 287-us body) ----
template <bool FINAL>
__global__ __launch_bounds__(NTHR, 4) void crf_pair_kernel(const f16* __restrict__ qin,
                                                           const f16* __restrict__ wu,
                                                           void* __restrict__ qout) {
    __shared__ __align__(16) f16 buf[SPX][CPAD];   // 46080 B; staged q, then reused for q'

    const int tid = threadIdx.x;          // 0..511
    const int ix = tid & (TW - 1);        // 0..31
    const int iy = tid >> 5;              // 0..15

    // XCD band swizzle: 1024 blocks; XCD (flat%8) owns 4 tile-rows per batch
    const int flat = blockIdx.x;
    const int band = flat & 7;
    const int within = flat >> 3;         // 0..127
    const int b = within >> 6;
    const int r = within & 63;
    const int x0 = (r & 15) * TW;
    const int y0 = (band * 4 + (r >> 4)) * TH;
    const int gx = x0 + ix;
    const int gy = y0 + iy;
    const size_t plane = (size_t)HH * WW;

    // ---- phase 1: async stage 24x40 q halo (4-px, for 2 iterations) ----
    const f16* qbase = qin + (size_t)b * plane * CPAD;
    f16* lbase = &buf[0][0];
    for (int idx = tid; idx < SCHUNK; idx += NTHR) {
        int px = idx / 3, h4 = idx - px * 3;
        int sly = px / SX, slx = px - sly * SX;
        int qy = refl(y0 - 4 + sly, HH);
        int qx = refl(x0 - 4 + slx, WW);
        const f16* g = qbase + ((size_t)(qy * WW + qx)) * CPAD + h4 * 8;
        __builtin_amdgcn_global_load_lds(
            (const __attribute__((address_space(1))) void*)g,
            (__attribute__((address_space(3))) void*)(lbase + (size_t)idx * 8),
            16, 0, 0);
    }

    // ---- fetch inner-pixel packed w+u (registers, used by BOTH iterations) ----
    const size_t pixoff = (size_t)b * plane + (size_t)gy * WW + gx;
    const half8* wp = (const half8*)(wu + pixoff * WUPAD);
    half8 wa0 = wp[0], wa1 = wp[1], wa2 = wp[2];
    half8 ui0 = wp[3], ui1 = wp[4], ui2 = wp[5];
    f16 wl = ui2[5];

    // ---- ring pixel (threads 0..207): coords + packed w+u ----
    const bool has_ring = tid < RING;
    int rly = 0, rlx = 0;
    half8 wr0 = {}, wr1 = {}, wr2 = {}, ur0 = {}, ur1 = {}, ur2 = {};
    f16 wrl = (f16)0.f;
    if (has_ring) {
        int t = tid;
        if (t < 72)       { rly = t / 36;       rlx = t % 36; }
        else if (t < 144) { t -= 72;  rly = 18 + t / 36; rlx = t % 36; }
        else              { t -= 144; rly = 2 + (t >> 2); int c = t & 3; rlx = (c < 2) ? c : (c + 32); }
        int rgy = y0 + rly - 2, rgx = x0 + rlx - 2;
        int cy = min(max(rgy, 0), HH - 1);
        int cx = min(max(rgx, 0), WW - 1);
        size_t rpo = (size_t)b * plane + (size_t)cy * WW + cx;
        const half8* wpr = (const half8*)(wu + rpo * WUPAD);
        wr0 = wpr[0]; wr1 = wpr[1]; wr2 = wpr[2];
        ur0 = wpr[3]; ur1 = wpr[4]; ur2 = wpr[5];
        wrl = ur2[5];
    }

    __syncthreads();   // staged q + register loads resident

    // ---- phase 2: iteration k over the extended 36x20 region (packed f16 MACs) ----
    half8 qr0, qr1, qr2;   // ring q' (packed f16)
    if (has_ring) {
        half2v acc2[11];
#pragma unroll
        for (int j = 0; j < 11; j++) acc2[j] = (half2v){(f16)0.f, (f16)0.f};
        CONV_ACC_PK(acc2, lbase, rly, rlx, SX, wr0, wr1, wr2, wrl);
        float l[NCH];
        LOGITS_FROM_PK(l, acc2, ur0, ur1, ur2);
        float m = l[0];
#pragma unroll
        for (int c = 1; c < NCH; c++) m = fmaxf(m, l[c]);
        float s = 0.f;
#pragma unroll
        for (int c = 0; c < NCH; c++) { l[c] = __expf(l[c] - m); s += l[c]; }
        float is = 1.0f / s;
#pragma unroll
        for (int k = 0; k < 8; k++) qr0[k] = (f16)(l[k] * is);
#pragma unroll
        for (int k = 0; k < 8; k++) qr1[k] = (f16)(l[8 + k] * is);
#pragma unroll
        for (int k = 0; k < 5; k++) qr2[k] = (f16)(l[16 + k] * is);
        qr2[5] = (f16)0.f; qr2[6] = (f16)0.f; qr2[7] = (f16)0.f;
    }

    half8 qi0, qi1, qi2;   // inner q' (packed f16)
    {
        half2v acc2[11];
#pragma unroll
        for (int j = 0; j < 11; j++) acc2[j] = (half2v){(f16)0.f, (f16)0.f};
        CONV_ACC_PK(acc2, lbase, iy + 2, ix + 2, SX, wa0, wa1, wa2, wl);
        float l[NCH];
        LOGITS_FROM_PK(l, acc2, ui0, ui1, ui2);
        float m = l[0];
#pragma unroll
        for (int c = 1; c < NCH; c++) m = fmaxf(m, l[c]);
        float s = 0.f;
#pragma unroll
        for (int c = 0; c < NCH; c++) { l[c] = __expf(l[c] - m); s += l[c]; }
        float is = 1.0f / s;
#pragma unroll
        for (int k = 0; k < 8; k++) qi0[k] = (f16)(l[k] * is);
#pragma unroll
        for (int k = 0; k < 8; k++) qi1[k] = (f16)(l[8 + k] * is);
#pragma unroll
        for (int k = 0; k < 5; k++) qi2[k] = (f16)(l[16 + k] * is);
        qi2[5] = (f16)0.f; qi2[6] = (f16)0.f; qi2[7] = (f16)0.f;
    }

    __syncthreads();   // all reads of staged q complete

    // ---- phase 3: park q' in LDS (reuse buf; layout [EPX][24], stride EX) ----
    {
        half8* d = (half8*)(lbase + ((size_t)(iy + 2) * EX + (ix + 2)) * CPAD);
        d[0] = qi0; d[1] = qi1; d[2] = qi2;
        if (has_ring) {
            half8* dr = (half8*)(lbase + ((size_t)rly * EX + rlx) * CPAD);
            dr[0] = qr0; dr[1] = qr1; dr[2] = qr2;
        }
    }

    __syncthreads();

    // ---- phase 4: iteration k+1 at inner pixels (w,u from registers) ----
    {
        int ry[KS], rx[KS];
#pragma unroll
        for (int d = 0; d < KS; d++) {
            ry[d] = refl(gy + d - 2, HH) - (y0 - 2);
            rx[d] = refl(gx + d - 2, WW) - (x0 - 2);
        }
        half2v acc2[11];
#pragma unroll
        for (int j = 0; j < 11; j++) acc2[j] = (half2v){(f16)0.f, (f16)0.f};
#pragma unroll
        for (int dy = 0; dy < KS; dy++) {
#pragma unroll
            for (int dx = 0; dx < KS; dx++) {
                const f16 wt_ = WSEL(wa0, wa1, wa2, wl, dy * KS + dx);
                const half2v wv_ = {wt_, wt_};
                const f16* tp = lbase + ((size_t)ry[dy] * EX + rx[dx]) * CPAD;
                half8 v0 = *(const half8*)(tp);
                half8 v1 = *(const half8*)(tp + 8);
                half8 v2 = *(const half8*)(tp + 16);
                acc2[0]  = __builtin_elementwise_fma(wv_, __builtin_shufflevector(v0, v0, 0, 1), acc2[0]);
                acc2[1]  = __builtin_elementwise_fma(wv_, __builtin_shufflevector(v0, v0, 2, 3), acc2[1]);
                acc2[2]  = __builtin_elementwise_fma(wv_, __builtin_shufflevector(v0, v0, 4, 5), acc2[2]);
                acc2[3]  = __builtin_elementwise_fma(wv_, __builtin_shufflevector(v0, v0, 6, 7), acc2[3]);
                acc2[4]  = __builtin_elementwise_fma(wv_, __builtin_shufflevector(v1, v1, 0, 1), acc2[4]);
                acc2[5]  = __builtin_elementwise_fma(wv_, __builtin_shufflevector(v1, v1, 2, 3), acc2[5]);
                acc2[6]  = __builtin_elementwise_fma(wv_, __builtin_shufflevector(v1, v1, 4, 5), acc2[6]);
                acc2[7]  = __builtin_elementwise_fma(wv_, __builtin_shufflevector(v1, v1, 6, 7), acc2[7]);
                acc2[8]  = __builtin_elementwise_fma(wv_, __builtin_shufflevector(v2, v2, 0, 1), acc2[8]);
                acc2[9]  = __builtin_elementwise_fma(wv_, __builtin_shufflevector(v2, v2, 2, 3), acc2[9]);
                acc2[10] = __builtin_elementwise_fma(wv_, __builtin_shufflevector(v2, v2, 4, 5), acc2[10]);
            }
        }
        float l[NCH];
        LOGITS_FROM_PK(l, acc2, ui0, ui1, ui2);
        float m = l[0];
#pragma unroll
        for (int c = 1; c < NCH; c++) m = fmaxf(m, l[c]);
        float s = 0.f;
#pragma unroll
        for (int c = 0; c < NCH; c++) { l[c] = __expf(l[c] - m); s += l[c]; }
        float is = 1.0f / s;

        if (FINAL) {
            float* qo = (float*)qout + (size_t)b * NCH * plane + (size_t)gy * WW + gx;
#pragma unroll
            for (int c = 0; c < NCH; c++) qo[c * plane] = l[c] * is;
        } else {
            half8* qo = (half8*)((f16*)qout + pixoff * CPAD);
            half8 o0, o1, o2;
#pragma unroll
            for (int k = 0; k < 8; k++) o0[k] = (f16)(l[k] * is);
#pragma unroll
            for (int k = 0; k < 8; k++) o1[k] = (f16)(l[8 + k] * is);
#pragma unroll
            for (int k = 0; k < 5; k++) o2[k] = (f16)(l[16 + k] * is);
            o2[5] = (f16)0.f; o2[6] = (f16)0.f; o2[7] = (f16)0.f;
            qo[0] = o0; qo[1] = o1; qo[2] = o2;
        }
    }
}

extern "C" void kernel_launch(void* const* d_in, const int* in_sizes, int n_in,
                              void* d_out, int out_size, void* d_ws, size_t ws_size,
                              hipStream_t stream) {
    const float* unary = (const float*)d_in[0];   // B,21,512,512
    const float* image = (const float*)d_in[1];   // B,3,512,512
    const float* edges = (const float*)d_in[2];   // B,512,512
    float* out = (float*)d_out;                   // B,21,512,512 fp32

    const size_t plane = (size_t)HH * WW;
    char* ws = (char*)d_ws;
    f16* wu = (f16*)ws;                                          // B*plane*48 f16 = 50.3 MB
    char* p1 = ws + sizeof(f16) * BATCH * plane * WUPAD;
    f16* qA = (f16*)p1;                                          // 25.2 MB
    f16* qB = qA + (size_t)BATCH * plane * CPAD;                 // 25.2 MB (total ~101 MB)

    dim3 gridW(WW / TXW, HH / TYW, BATCH);
    dim3 blockW(TXW, TYW, 1);
    setup_kernel<<<gridW, blockW, 0, stream>>>(image, edges, unary, wu, qA);

    const int nblk = (WW / TW) * (HH / TH) * BATCH;   // 1024
    f16* qa = qA;
    f16* qb = qB;
    const int npairs = NUM_ITERS / 2;                 // 5
    for (int it = 0; it < npairs - 1; it++) {
        crf_pair_kernel<false><<<nblk, NTHR, 0, stream>>>(qa, wu, (void*)qb);
        f16* t = qa; qa = qb; qb = t;
    }
    crf_pair_kernel<true><<<nblk, NTHR, 0, stream>>>(qa, wu, (void*)out);
}